// Round 7
// baseline (25.174 us; speedup 1.0000x reference)
//
#include <hip/hip_runtime.h>

#define BNEPS 1e-5f

// ---------------------------------------------------------------------------
// The reference network's output is batch-constant: binarize(relu(x)) == +1
// everywhere, so the fire module's outputs are data-independent. We compute
// feat F[128] and logits L[1000] once, then broadcast over the 8192 rows.
//
// Measured sync costs on this harness: CG grid.sync ~180us (R3), 1k-poller
// flag spin ~70us/phase (R4), int64-atomic fan-in ~+6us (R5). Dispatch
// boundaries (~2-3.5us/node) are the cheapest device-wide sync -> minimize
// node count. TWO dispatches:
//   K1 feat_partial: 512 blocks = 4 K-splits x 128 outputs; block (s,o)
//      writes partial_s[o] = w1[o, slice] . hb[slice] to ws[s*128+o].
//   K2 bcast_logits: 544 blocks.
//      blocks 0..511: (rg, j) = 64 rows x 250 logit cols. Re-sum partials
//        (fixed order) -> F -> Cc, compute own 250-logit slice from w2
//        (128 KB L2/block; 65 MB total), store 64x1000B slices.
//        All row-groups of column-group j compute the identical L-slice with
//        identical expression order -> bit-deterministic.
//      blocks 512..543: feat section; re-derive F (same fixed-order sum ->
//        bitwise equal across blocks), broadcast 8192 float4 each.
//
// ws layout (floats): [0..512) = K-split partials of F.
// ---------------------------------------------------------------------------

__device__ __forceinline__ float wave_reduce(float acc) {
    #pragma unroll
    for (int off = 32; off > 0; off >>= 1)
        acc += __shfl_down(acc, off);
    return acc;
}

// ------------------------------- K1 ----------------------------------------

__global__ __launch_bounds__(256) void feat_partial_kernel(
    const float* __restrict__ w_e1, const float* __restrict__ b_e1,
    const float* __restrict__ w_pw,
    const float* __restrict__ bnpw_g, const float* __restrict__ bnpw_b,
    const float* __restrict__ bnpw_m, const float* __restrict__ bnpw_v,
    const float* __restrict__ bnf_g, const float* __restrict__ bnf_b,
    const float* __restrict__ bnf_m, const float* __restrict__ bnf_v,
    const float* __restrict__ w1,
    float* __restrict__ ws)
{
    __shared__ __align__(16) float cst[64];    // channel consts for this slice
    __shared__ __align__(16) float hbs[576];   // hb slice
    __shared__ float red[4];

    const int tid = threadIdx.x;
    const int s   = blockIdx.x & 3;            // K-split 0..3
    const int o   = blockIdx.x >> 2;           // output 0..127
    const int f0  = s * 576;                   // f-range base
    const int ch0 = s * 64;                    // channel base

    // hoist the w1 slice load (independent of everything below)
    float4 wreg = make_float4(0.f, 0.f, 0.f, 0.f);
    if (tid < 144)
        wreg = reinterpret_cast<const float4*>(w1 + o * 2304 + f0)[tid];

    // channel constants for the 64 channels of this slice
    if (tid < 64) {
        const int ch = ch0 + tid;
        float r;
        if (ch < 128) {
            const float4* we = reinterpret_cast<const float4*>(w_e1 + ch * 32);
            float ssum = 0.f;
            #pragma unroll
            for (int q = 0; q < 8; ++q) {
                float4 a = we[q];
                ssum += ((a.x >= 0.f) ? 1.f : -1.f) + ((a.y >= 0.f) ? 1.f : -1.f)
                      + ((a.z >= 0.f) ? 1.f : -1.f) + ((a.w >= 0.f) ? 1.f : -1.f);
            }
            r = fmaxf(ssum + b_e1[ch], 0.f);
        } else {
            const int c2 = ch - 128;
            const float4* wp = reinterpret_cast<const float4*>(w_pw + c2 * 32);
            float psum = 0.f;
            #pragma unroll
            for (int q = 0; q < 8; ++q) {
                float4 a = wp[q];
                psum += ((a.x >= 0.f) ? 1.f : -1.f) + ((a.y >= 0.f) ? 1.f : -1.f)
                      + ((a.z >= 0.f) ? 1.f : -1.f) + ((a.w >= 0.f) ? 1.f : -1.f);
            }
            float inv = bnpw_g[c2] * rsqrtf(bnpw_v[c2] + BNEPS);
            r = fmaxf((psum - bnpw_m[c2]) * inv + bnpw_b[c2], 0.f);
        }
        cst[tid] = r;
    }
    __syncthreads();

    // hb slice: 576 values
    #pragma unroll
    for (int r = 0; r < 3; ++r) {
        int fl = tid + 256 * r;
        if (fl < 576) {
            int f = f0 + fl;
            float v = cst[fl / 9];
            float inv = bnf_g[f] * rsqrtf(bnf_v[f] + BNEPS);
            hbs[fl] = (v - bnf_m[f]) * inv + bnf_b[f];
        }
    }
    __syncthreads();

    // partial dot: 144 float4 terms
    float acc = 0.f;
    if (tid < 144) {
        float4 h = reinterpret_cast<const float4*>(hbs)[tid];
        acc = wreg.x * h.x + wreg.y * h.y + wreg.z * h.z + wreg.w * h.w;
    }
    acc = wave_reduce(acc);
    const int lane = tid & 63, wave = tid >> 6;
    if (lane == 0) red[wave] = acc;
    __syncthreads();
    if (tid == 0)
        ws[s * 128 + o] = (red[0] + red[1]) + (red[2] + red[3]);
}

// ------------------------------- K2 ----------------------------------------

__global__ __launch_bounds__(256) void bcast_logits_kernel(
    const float* __restrict__ ws, const float* __restrict__ b1,
    const float* __restrict__ bnc_g, const float* __restrict__ bnc_b,
    const float* __restrict__ bnc_m, const float* __restrict__ bnc_v,
    const float* __restrict__ w2, const float* __restrict__ b2,
    float* __restrict__ out)
{
    const int tid = threadIdx.x;
    const int b   = blockIdx.x;

    if (b < 512) {
        // ------- logits section: 64 rows x 250 columns per block -------
        const int j  = b & 3;        // column group 0..3
        const int rg = b >> 2;       // row group 0..127
        __shared__ __align__(16) float sC[128];
        __shared__ __align__(16) float sL[256];   // 250 used

        if (tid < 128) {
            // fixed-order partial sum (must match feat-section expression)
            float F = ((ws[tid] + ws[128 + tid]) + (ws[256 + tid] + ws[384 + tid]))
                      + b1[tid];
            float r = fmaxf(F, 0.f);
            float inv = bnc_g[tid] * rsqrtf(bnc_v[tid] + BNEPS);
            sC[tid] = (r - bnc_m[tid]) * inv + bnc_b[tid];
        }
        __syncthreads();

        if (tid < 250) {
            const int n = j * 250 + tid;
            const float4* __restrict__ wr = reinterpret_cast<const float4*>(w2 + n * 128);
            const float4* c4 = reinterpret_cast<const float4*>(sC);
            float ax = 0.f, ay = 0.f, az = 0.f, aw = 0.f;
            #pragma unroll 8
            for (int q = 0; q < 32; ++q) {
                float4 w = wr[q];
                float4 c = c4[q];
                ax += w.x * c.x; ay += w.y * c.y; az += w.z * c.z; aw += w.w * c.w;
            }
            sL[tid] = (ax + ay) + (az + aw) + b2[n];
        }
        __syncthreads();

        // stores: 64 rows, each a contiguous 1000 B slice (125 float2)
        const float2* sL2 = reinterpret_cast<const float2*>(sL);
        const size_t rowbase = (size_t)rg * 64;
        const int colbase = j * 250;
        for (int i = tid; i < 64 * 125; i += 256) {
            int r = i / 125;
            int c = i - r * 125;
            size_t addr = (rowbase + r) * 1000 + colbase + c * 2;
            *reinterpret_cast<float2*>(out + addr) = sL2[c];
        }
    } else {
        // ------- feat section: blocks 512..543 -------
        __shared__ __align__(16) float sF[128];
        if (tid < 128) {
            // same fixed-order sum as above -> bitwise-identical F
            sF[tid] = ((ws[tid] + ws[128 + tid]) + (ws[256 + tid] + ws[384 + tid]))
                      + b1[tid];
        }
        __syncthreads();

        const float4* sF4 = reinterpret_cast<const float4*>(sF);
        float4* out4 = reinterpret_cast<float4*>(out);
        const int base = 2048000 + (b - 512) * 8192;   // float4 units
        for (int i = tid; i < 8192; i += 256)
            out4[base + i] = sF4[i & 31];
    }
}

// ================================ launch ===================================

extern "C" void kernel_launch(void* const* d_in, const int* in_sizes, int n_in,
                              void* d_out, int out_size, void* d_ws, size_t ws_size,
                              hipStream_t stream) {
    (void)in_sizes; (void)n_in; (void)out_size; (void)ws_size;

    const float* w_e1  = (const float*)d_in[7];
    const float* b_e1  = (const float*)d_in[8];
    const float* w_pw  = (const float*)d_in[14];
    const float* bnpw_g = (const float*)d_in[15];
    const float* bnpw_b = (const float*)d_in[16];
    const float* bnpw_m = (const float*)d_in[17];
    const float* bnpw_v = (const float*)d_in[18];
    const float* bnf_g = (const float*)d_in[19];
    const float* bnf_b = (const float*)d_in[20];
    const float* bnf_m = (const float*)d_in[21];
    const float* bnf_v = (const float*)d_in[22];
    const float* w1    = (const float*)d_in[23];
    const float* b1    = (const float*)d_in[24];
    const float* bnc_g = (const float*)d_in[25];
    const float* bnc_b = (const float*)d_in[26];
    const float* bnc_m = (const float*)d_in[27];
    const float* bnc_v = (const float*)d_in[28];
    const float* w2    = (const float*)d_in[29];
    const float* b2    = (const float*)d_in[30];

    float* ws  = (float*)d_ws;
    float* out = (float*)d_out;

    hipLaunchKernelGGL(feat_partial_kernel, dim3(512), dim3(256), 0, stream,
                       w_e1, b_e1, w_pw,
                       bnpw_g, bnpw_b, bnpw_m, bnpw_v,
                       bnf_g, bnf_b, bnf_m, bnf_v,
                       w1, ws);

    hipLaunchKernelGGL(bcast_logits_kernel, dim3(544), dim3(256), 0, stream,
                       ws, b1, bnc_g, bnc_b, bnc_m, bnc_v, w2, b2, out);
}

// Round 9
// 19.872 us; speedup vs baseline: 1.2668x; 1.2668x over previous
//
#include <hip/hip_runtime.h>

#define BNEPS 1e-5f

// ---------------------------------------------------------------------------
// The reference network's output is batch-constant: binarize(relu(x)) == +1
// everywhere, so the fire module's outputs are data-independent. We compute
// feat F[128] and logits L[1000] once, then broadcast over the 8192 rows.
//
// Measured on this harness: CG grid.sync ~180us (R3), 1k-poller flag spin
// ~70us/phase (R4), int64-atomic fan-in ~+6us (R5), redundant-compute 2-node
// fusion +4.3us (R7). Dispatch boundaries win; R6's 3-dispatch chain is the
// local optimum. This round: R6 + nontemporal stores on the output stream
// (write-once data; avoid L2 write-allocate pollution). NT builtin needs a
// native clang vector type, not HIP_vector_type.
//
// ws layout (floats): [0..512) partials | [1024..2024) L
// ---------------------------------------------------------------------------

typedef float f32x4 __attribute__((ext_vector_type(4)));

__device__ __forceinline__ float wave_reduce(float acc) {
    #pragma unroll
    for (int off = 32; off > 0; off >>= 1)
        acc += __shfl_down(acc, off);
    return acc;
}

// ------------------------------- K1 ----------------------------------------

__global__ __launch_bounds__(256) void feat_partial_kernel(
    const float* __restrict__ w_e1, const float* __restrict__ b_e1,
    const float* __restrict__ w_pw,
    const float* __restrict__ bnpw_g, const float* __restrict__ bnpw_b,
    const float* __restrict__ bnpw_m, const float* __restrict__ bnpw_v,
    const float* __restrict__ bnf_g, const float* __restrict__ bnf_b,
    const float* __restrict__ bnf_m, const float* __restrict__ bnf_v,
    const float* __restrict__ w1,
    float* __restrict__ ws)
{
    __shared__ __align__(16) float cst[64];    // channel consts for this slice
    __shared__ __align__(16) float hbs[576];   // hb slice
    __shared__ float red[4];

    const int tid = threadIdx.x;
    const int s   = blockIdx.x & 3;            // K-split 0..3
    const int o   = blockIdx.x >> 2;           // output 0..127
    const int f0  = s * 576;                   // f-range base
    const int ch0 = s * 64;                    // channel base

    // hoist the w1 slice load (independent of everything below)
    float4 wreg = make_float4(0.f, 0.f, 0.f, 0.f);
    if (tid < 144)
        wreg = reinterpret_cast<const float4*>(w1 + o * 2304 + f0)[tid];

    // channel constants for the 64 channels of this slice
    if (tid < 64) {
        const int ch = ch0 + tid;
        float r;
        if (ch < 128) {
            const float4* we = reinterpret_cast<const float4*>(w_e1 + ch * 32);
            float ssum = 0.f;
            #pragma unroll
            for (int q = 0; q < 8; ++q) {
                float4 a = we[q];
                ssum += ((a.x >= 0.f) ? 1.f : -1.f) + ((a.y >= 0.f) ? 1.f : -1.f)
                      + ((a.z >= 0.f) ? 1.f : -1.f) + ((a.w >= 0.f) ? 1.f : -1.f);
            }
            r = fmaxf(ssum + b_e1[ch], 0.f);
        } else {
            const int c2 = ch - 128;
            const float4* wp = reinterpret_cast<const float4*>(w_pw + c2 * 32);
            float psum = 0.f;
            #pragma unroll
            for (int q = 0; q < 8; ++q) {
                float4 a = wp[q];
                psum += ((a.x >= 0.f) ? 1.f : -1.f) + ((a.y >= 0.f) ? 1.f : -1.f)
                      + ((a.z >= 0.f) ? 1.f : -1.f) + ((a.w >= 0.f) ? 1.f : -1.f);
            }
            float inv = bnpw_g[c2] * rsqrtf(bnpw_v[c2] + BNEPS);
            r = fmaxf((psum - bnpw_m[c2]) * inv + bnpw_b[c2], 0.f);
        }
        cst[tid] = r;
    }
    __syncthreads();

    // hb slice: 576 values
    #pragma unroll
    for (int r = 0; r < 3; ++r) {
        int fl = tid + 256 * r;
        if (fl < 576) {
            int f = f0 + fl;
            float v = cst[fl / 9];
            float inv = bnf_g[f] * rsqrtf(bnf_v[f] + BNEPS);
            hbs[fl] = (v - bnf_m[f]) * inv + bnf_b[f];
        }
    }
    __syncthreads();

    // partial dot: 144 float4 terms
    float acc = 0.f;
    if (tid < 144) {
        float4 h = reinterpret_cast<const float4*>(hbs)[tid];
        acc = wreg.x * h.x + wreg.y * h.y + wreg.z * h.z + wreg.w * h.w;
    }
    acc = wave_reduce(acc);
    const int lane = tid & 63, wave = tid >> 6;
    if (lane == 0) red[wave] = acc;
    __syncthreads();
    if (tid == 0)
        ws[s * 128 + o] = (red[0] + red[1]) + (red[2] + red[3]);
}

// ------------------------------- K2 ----------------------------------------

__global__ __launch_bounds__(256) void logits_kernel(
    const float* __restrict__ b1,
    const float* __restrict__ bnc_g, const float* __restrict__ bnc_b,
    const float* __restrict__ bnc_m, const float* __restrict__ bnc_v,
    const float* __restrict__ w2, const float* __restrict__ b2,
    float* __restrict__ ws)
{
    __shared__ __align__(16) float sC[128];
    const int tid = threadIdx.x;

    // hoist w2 loads (independent of ws)
    const int lane = tid & 63, wave = tid >> 6;
    const int n = blockIdx.x * 4 + wave;   // 250*4 = 1000
    float2 w = reinterpret_cast<const float2*>(w2 + n * 128)[lane];

    if (tid < 128) {
        // fixed-order partial sum -- must match K3's expression exactly
        float F = ((ws[tid] + ws[128 + tid]) + (ws[256 + tid] + ws[384 + tid]))
                  + b1[tid];
        float r = fmaxf(F, 0.f);
        float inv = bnc_g[tid] * rsqrtf(bnc_v[tid] + BNEPS);
        sC[tid] = (r - bnc_m[tid]) * inv + bnc_b[tid];
    }
    __syncthreads();

    float acc = w.x * sC[2 * lane] + w.y * sC[2 * lane + 1];
    acc = wave_reduce(acc);
    if (lane == 0) ws[1024 + n] = acc + b2[n];
}

// ------------------------------- K3 ----------------------------------------

__global__ __launch_bounds__(256) void broadcast_out(
    const float* __restrict__ ws, const float* __restrict__ b1,
    float* __restrict__ out)
{
    __shared__ __align__(16) float sL[1000];
    __shared__ __align__(16) float sF[128];
    const int tid = threadIdx.x;

    for (int i = tid; i < 1000; i += 256) sL[i] = ws[1024 + i];
    if (tid < 128) {
        // same fixed-order sum as K2 -> bitwise-identical F
        sF[tid] = ((ws[tid] + ws[128 + tid]) + (ws[256 + tid] + ws[384 + tid]))
                  + b1[tid];
    }
    __syncthreads();

    const f32x4* sL4 = reinterpret_cast<const f32x4*>(sL);
    const f32x4* sF4 = reinterpret_cast<const f32x4*>(sF);
    f32x4* out4 = reinterpret_cast<f32x4*>(out);

    const int TOT = 2310144;   // 9,240,576 floats / 4
    const int LOG = 2048000;   // 8,192,000 floats / 4 (logits section)

    for (int i = blockIdx.x * blockDim.x + tid; i < TOT;
         i += gridDim.x * blockDim.x) {
        f32x4 v;
        if (i < LOG) v = sL4[i % 250];          // 250 float4 per logits row
        else         v = sF4[(i - LOG) & 31];   // 32 float4 per feat row
        __builtin_nontemporal_store(v, &out4[i]);   // write-once stream: NT
    }
}

// ================================ launch ===================================

extern "C" void kernel_launch(void* const* d_in, const int* in_sizes, int n_in,
                              void* d_out, int out_size, void* d_ws, size_t ws_size,
                              hipStream_t stream) {
    (void)in_sizes; (void)n_in; (void)out_size; (void)ws_size;

    const float* w_e1  = (const float*)d_in[7];
    const float* b_e1  = (const float*)d_in[8];
    const float* w_pw  = (const float*)d_in[14];
    const float* bnpw_g = (const float*)d_in[15];
    const float* bnpw_b = (const float*)d_in[16];
    const float* bnpw_m = (const float*)d_in[17];
    const float* bnpw_v = (const float*)d_in[18];
    const float* bnf_g = (const float*)d_in[19];
    const float* bnf_b = (const float*)d_in[20];
    const float* bnf_m = (const float*)d_in[21];
    const float* bnf_v = (const float*)d_in[22];
    const float* w1    = (const float*)d_in[23];
    const float* b1    = (const float*)d_in[24];
    const float* bnc_g = (const float*)d_in[25];
    const float* bnc_b = (const float*)d_in[26];
    const float* bnc_m = (const float*)d_in[27];
    const float* bnc_v = (const float*)d_in[28];
    const float* w2    = (const float*)d_in[29];
    const float* b2    = (const float*)d_in[30];

    float* ws  = (float*)d_ws;
    float* out = (float*)d_out;

    hipLaunchKernelGGL(feat_partial_kernel, dim3(512), dim3(256), 0, stream,
                       w_e1, b_e1, w_pw,
                       bnpw_g, bnpw_b, bnpw_m, bnpw_v,
                       bnf_g, bnf_b, bnf_m, bnf_v,
                       w1, ws);

    hipLaunchKernelGGL(logits_kernel, dim3(250), dim3(256), 0, stream,
                       b1, bnc_g, bnc_b, bnc_m, bnc_v, w2, b2, ws);

    hipLaunchKernelGGL(broadcast_out, dim3(2048), dim3(256), 0, stream,
                       ws, b1, out);
}